// Round 1
// baseline (2214.024 us; speedup 1.0000x reference)
//
#include <hip/hip_runtime.h>
#include <math.h>

#define S_   512
#define D_   512
#define SD_  (512*512)
#define BSD_ (16*512*512)

__device__ __forceinline__ float sigmoidf_(float x) { return 1.0f / (1.0f + __expf(-x)); }

// ---------------------------------------------------------------------------
// Generic fp32 GEMM: C[bz] = epi( A[bz] (MxK, optionally transposed) * B[bz] (KxN) )
// Tile 128x128, BK=8, 256 threads, 8x8 per thread, register-prefetch double buffer.
// EPI: 0=store, 1=+bias, 2=sigmoid(+Cin), 3=+Cin, 4=((acc+bS*bias+Cin)*invden, PReLU),
//      5=C+=acc, 6=sigmoid(+bias)
// ---------------------------------------------------------------------------
template<int EPI, int TA>
__global__ __launch_bounds__(256)
void gemm_k(const float* __restrict__ A, const float* __restrict__ Bm, float* __restrict__ C,
            const int M, const int N, const int K,
            const long sA, const long sB, const long sC,
            const int lda, const int ldb, const int ldc,
            const float* __restrict__ bias, const float biasScale,
            const float* __restrict__ Cin, const long sCin,
            const float* __restrict__ invden,
            const float* __restrict__ prelu, const int prelu_idx)
{
    __shared__ float As[8][132];
    __shared__ float Bs[8][132];
    const int bz = blockIdx.z;
    const float* Ab = A + (long)bz * sA;
    const float* Bb = Bm + (long)bz * sB;
    float* Cb = C + (long)bz * sC;
    const int m0 = blockIdx.y * 128;
    const int n0 = blockIdx.x * 128;
    const int tid = threadIdx.x;
    const int tx = tid & 15, ty = tid >> 4;

    const int kB = tid >> 5;          // 0..7
    const int nB = (tid & 31) << 2;   // 0..124
    const int mA = tid >> 1;          // 0..127
    const int kA = (tid & 1) << 2;    // 0 or 4

    float acc[8][8];
#pragma unroll
    for (int i = 0; i < 8; ++i)
#pragma unroll
        for (int j = 0; j < 8; ++j) acc[i][j] = 0.0f;

    const int nk = K >> 3;
    float4 aR, bR;
    if (TA) aR = *(const float4*)(Ab + (long)kB * lda + (m0 + nB));
    else    aR = *(const float4*)(Ab + (long)(m0 + mA) * lda + kA);
    bR = *(const float4*)(Bb + (long)kB * ldb + (n0 + nB));

    for (int kt = 0; kt < nk; ++kt) {
        __syncthreads();
        if (TA) { *(float4*)&As[kB][nB] = aR; }
        else { As[kA][mA] = aR.x; As[kA+1][mA] = aR.y; As[kA+2][mA] = aR.z; As[kA+3][mA] = aR.w; }
        *(float4*)&Bs[kB][nB] = bR;
        __syncthreads();
        if (kt + 1 < nk) {
            const int k0 = (kt + 1) << 3;
            if (TA) aR = *(const float4*)(Ab + (long)(k0 + kB) * lda + (m0 + nB));
            else    aR = *(const float4*)(Ab + (long)(m0 + mA) * lda + (k0 + kA));
            bR = *(const float4*)(Bb + (long)(k0 + kB) * ldb + (n0 + nB));
        }
#pragma unroll
        for (int k = 0; k < 8; ++k) {
            const float4 av0 = *(const float4*)&As[k][ty << 3];
            const float4 av1 = *(const float4*)&As[k][(ty << 3) + 4];
            const float4 bv0 = *(const float4*)&Bs[k][tx << 3];
            const float4 bv1 = *(const float4*)&Bs[k][(tx << 3) + 4];
            const float a[8] = {av0.x, av0.y, av0.z, av0.w, av1.x, av1.y, av1.z, av1.w};
            const float b[8] = {bv0.x, bv0.y, bv0.z, bv0.w, bv1.x, bv1.y, bv1.z, bv1.w};
#pragma unroll
            for (int i = 0; i < 8; ++i)
#pragma unroll
                for (int j = 0; j < 8; ++j) acc[i][j] = fmaf(a[i], b[j], acc[i][j]);
        }
    }

    const float pa = (EPI == 4) ? prelu[prelu_idx] : 0.0f;
#pragma unroll
    for (int i = 0; i < 8; ++i) {
        const int m = m0 + (ty << 3) + i;
        const long rowb = (long)m * ldc;
        float idv = 1.0f;
        if (EPI == 4) idv = invden[(long)bz * M + m];
        const long cinRow = (EPI == 2 || EPI == 3 || EPI == 4) ? ((long)bz * sCin + rowb) : 0;
#pragma unroll
        for (int jj = 0; jj < 2; ++jj) {
            const int n = n0 + (tx << 3) + (jj << 2);
            float4 v;
            float* vp = (float*)&v;
            float4 oldv = make_float4(0.f, 0.f, 0.f, 0.f);
            if (EPI == 5) oldv = *(const float4*)(Cb + rowb + n);
            const float* op = (const float*)&oldv;
#pragma unroll
            for (int q = 0; q < 4; ++q) {
                float x = acc[i][(jj << 2) + q];
                const int nn = n + q;
                if (EPI == 1) x += bias[nn];
                else if (EPI == 2) x = sigmoidf_(x + Cin[cinRow + nn]);
                else if (EPI == 3) x += Cin[cinRow + nn];
                else if (EPI == 4) {
                    x = (x + biasScale * bias[nn] + Cin[cinRow + nn]) * idv;
                    x = (x >= 0.0f) ? x : pa * x;
                }
                else if (EPI == 5) x += op[q];
                else if (EPI == 6) x = sigmoidf_(x + bias[nn]);
                vp[q] = x;
            }
            *(float4*)(Cb + rowb + n) = v;
        }
    }
}

// ---------------------------------------------------------------------------
// E0: per (b,s) row: invden = 1/(sum_j adj + 1); frontadj = sum_j adj*depmap;
//     dcol = one-hot col of depmap; domain/redomain masks + selected index.
// ---------------------------------------------------------------------------
__global__ __launch_bounds__(256)
void e0_k(const float* __restrict__ adj, const float* __restrict__ depmap,
          const float* __restrict__ domain_id, const float* __restrict__ redomain_id,
          float* __restrict__ invden, float* __restrict__ fa, int* __restrict__ dcol,
          int* __restrict__ dm, int* __restrict__ dsel, int* __restrict__ rm, int* __restrict__ rsel)
{
    const int bs = blockIdx.x;
    const int t = threadIdx.x;
    const float* arow = adj + (long)bs * 512;
    const float* drow = depmap + (long)bs * 512;
    __shared__ float red[256];
    __shared__ int scol;
    if (t == 0) scol = 0;
    const float a0 = arow[t], a1 = arow[t + 256];
    const float p0 = drow[t], p1 = drow[t + 256];
    if (p0 > 0.5f) scol = t;
    if (p1 > 0.5f) scol = t + 256;
    red[t] = a0 + a1;
    __syncthreads();
    for (int off = 128; off > 0; off >>= 1) { if (t < off) red[t] += red[t + off]; __syncthreads(); }
    if (t == 0) invden[bs] = 1.0f / (red[0] + 1.0f);
    __syncthreads();
    red[t] = a0 * p0 + a1 * p1;
    __syncthreads();
    for (int off = 128; off > 0; off >>= 1) { if (t < off) red[t] += red[t + off]; __syncthreads(); }
    if (t == 0) {
        fa[bs] = red[0];
        dcol[bs] = scol;
        const float* q = domain_id + (long)bs * 8;
        float s = 0.f; int sel = 0;
        for (int k = 0; k < 8; ++k) { float v = q[k]; s += v; if (v > 0.5f) sel = k; }
        dm[bs] = (s > 0.5f) ? 1 : 0; dsel[bs] = sel;
        const float* r = redomain_id + (long)bs * 8;
        s = 0.f; sel = 0;
        for (int k = 0; k < 8; ++k) { float v = r[k]; s += v; if (v > 0.5f) sel = k; }
        rm[bs] = (s > 0.5f) ? 1 : 0; rsel[bs] = sel;
    }
}

// backadj[b,s] = adj[b, dcol[b,s], s]
__global__ void e0b_k(const float* __restrict__ adj, const int* __restrict__ dcol, float* __restrict__ ba)
{
    const int bs = blockIdx.x * 256 + threadIdx.x;  // 8192
    const int b = bs >> 9, s = bs & 511;
    ba[bs] = adj[((long)b * 512 + dcol[bs]) * 512 + s];
}

// pooled[b,k,d] = max_s (domain[b,s,k] ? -10000 : OUT[b,s,d])
__global__ __launch_bounds__(512)
void pool_k(const float* __restrict__ OUT, const int* __restrict__ domain, float* __restrict__ pooled)
{
    const int bk = blockIdx.x;           // 0..127
    const int b = bk >> 3, k = bk & 7;
    const int d = threadIdx.x;
    const float* Ob = OUT + (long)b * SD_;
    const int* db = domain + ((long)b * 512) * 8 + k;
    float mx = -1e30f;
    for (int s = 0; s < 512; ++s) {
        const float v = db[(long)s * 8] ? -10000.0f : Ob[(long)s * 512 + d];
        mx = fmaxf(mx, v);
    }
    pooled[(long)bk * 512 + d] = mx;
}

// FO = dm ? DG[b,dsel,:] : OUTp ;  RB = rm ? DG[b,rsel,:] : RB
__global__ void e1_k(const float* __restrict__ OUTp, float* __restrict__ FO, float* __restrict__ RB,
                     const float* __restrict__ DG, const int* __restrict__ dm, const int* __restrict__ dsel,
                     const int* __restrict__ rm, const int* __restrict__ rsel)
{
    const long idx = (long)blockIdx.x * 256 + threadIdx.x;
    const int bs = (int)(idx >> 9);
    const int d = (int)(idx & 511);
    const int b = bs >> 9;
    const float fo = dm[bs] ? DG[((long)(b * 8 + dsel[bs]) << 9) + d] : OUTp[idx];
    const float rb = rm[bs] ? DG[((long)(b * 8 + rsel[bs]) << 9) + d] : RB[idx];
    FO[idx] = fo;
    RB[idx] = rb;
}

// FO = frontadj*FG*FO (Xf in place); OxR = OUTp * rel
__global__ void e2_k(float* __restrict__ FO, const float* __restrict__ FG, const float* __restrict__ fa,
                     const float* __restrict__ OUTp, const float* __restrict__ rel, float* __restrict__ OxR)
{
    const long idx = (long)blockIdx.x * 256 + threadIdx.x;
    const int bs = (int)(idx >> 9);
    FO[idx] = fa[bs] * FG[idx] * FO[idx];
    OxR[idx] = OUTp[idx] * rel[idx];
}

// DL += backadj * BG * RB
__global__ void e3_k(float* __restrict__ DL, const float* __restrict__ ba,
                     const float* __restrict__ BG, const float* __restrict__ RB)
{
    const long idx = (long)blockIdx.x * 256 + threadIdx.x;
    const int bs = (int)(idx >> 9);
    DL[idx] += ba[bs] * BG[idx] * RB[idx];
}

// out = gcn + b_out
__global__ void e4_k(float* __restrict__ out, const float* __restrict__ gcn, const float* __restrict__ b_out)
{
    const long idx = (long)blockIdx.x * 256 + threadIdx.x;
    out[idx] = gcn[idx] + b_out[idx & 511];
}

extern "C" void kernel_launch(void* const* d_in, const int* in_sizes, int n_in,
                              void* d_out, int out_size, void* d_ws, size_t ws_size,
                              hipStream_t stream)
{
    const float* adj         = (const float*)d_in[0];
    const int*   domain      = (const int*)d_in[1];     // bool -> int32 per harness convention
    const float* domain_id   = (const float*)d_in[2];
    const float* redomain_id = (const float*)d_in[3];
    const float* frontrel    = (const float*)d_in[4];
    const float* backrel     = (const float*)d_in[5];
    const float* depmap      = (const float*)d_in[6];
    const float* rel         = (const float*)d_in[7];
    const float* gcn         = (const float*)d_in[8];
    // d_in[9] mask: all ones, unused by the math
    const float* W_layers    = (const float*)d_in[10];
    const float* b_layers    = (const float*)d_in[11];
    const float* prelu_a     = (const float*)d_in[12];
    const float* W_dg        = (const float*)d_in[13];
    const float* b_dg        = (const float*)d_in[14];
    const float* W_mg        = (const float*)d_in[15];
    const float* b_mg        = (const float*)d_in[16];
    const float* W_out       = (const float*)d_in[17];
    const float* b_out       = (const float*)d_in[18];
    float* out = (float*)d_out;

    char* w = (char*)d_ws;
    auto alloc = [&](size_t bytes) { void* p = (void*)w; w += (bytes + 255) & ~(size_t)255; return p; };
    const size_t BSDb = (size_t)BSD_ * 4;
    float* outsA[3];
    outsA[0] = (float*)alloc(BSDb);
    outsA[1] = (float*)alloc(BSDb);
    outsA[2] = (float*)alloc(BSDb);
    float* RB  = (float*)alloc(BSDb);
    float* FO  = (float*)alloc(BSDb);
    float* FG  = (float*)alloc(BSDb);   // also reused as (Ax+outputs) buffer
    float* BG  = (float*)alloc(BSDb);
    float* OxR = (float*)alloc(BSDb);
    float* DL  = (float*)alloc(BSDb);
    float* FB  = (float*)alloc(BSDb);
    float* BB  = (float*)alloc(BSDb);
    float* pooled = (float*)alloc((size_t)16 * 8 * 512 * 4);
    float* DG     = (float*)alloc((size_t)16 * 8 * 512 * 4);
    float* invden = (float*)alloc(8192 * 4);
    float* fa     = (float*)alloc(8192 * 4);
    float* ba     = (float*)alloc(8192 * 4);
    int* dcol = (int*)alloc(8192 * 4);
    int* dm   = (int*)alloc(8192 * 4);
    int* dsel = (int*)alloc(8192 * 4);
    int* rm   = (int*)alloc(8192 * 4);
    int* rsel = (int*)alloc(8192 * 4);

    e0_k<<<8192, 256, 0, stream>>>(adj, depmap, domain_id, redomain_id, invden, fa, dcol, dm, dsel, rm, rsel);
    e0b_k<<<32, 256, 0, stream>>>(adj, dcol, ba);

    const dim3 blk(256);
    const dim3 gFlat(4, 64, 1);   // 8192x512
    const dim3 gBat(4, 4, 16);    // batched 512x512

    // Layer-invariant: FB/BB = {front,back}rel @ W_mg[D:2D] + b_mg
    gemm_k<1, 0><<<gFlat, blk, 0, stream>>>(frontrel, W_mg + SD_, FB, 8192, 512, 512, 0, 0, 0,
                                            512, 512, 512, b_mg, 1.0f, nullptr, 0, nullptr, nullptr, 0);
    gemm_k<1, 0><<<gFlat, blk, 0, stream>>>(backrel, W_mg + SD_, BB, 8192, 512, 512, 0, 0, 0,
                                            512, 512, 512, b_mg, 1.0f, nullptr, 0, nullptr, nullptr, 0);

    const float* OUTp = gcn;
    for (int l = 0; l < 3; ++l) {
        // RB = rel @ outputs
        gemm_k<0, 0><<<gBat, blk, 0, stream>>>(rel, OUTp, RB, 512, 512, 512, SD_, SD_, SD_,
                                               512, 512, 512, nullptr, 0.f, nullptr, 0, nullptr, nullptr, 0);
        // pooled + domain gate
        pool_k<<<128, 512, 0, stream>>>(OUTp, domain, pooled);
        gemm_k<6, 0><<<dim3(4, 1, 1), blk, 0, stream>>>(pooled, W_dg, DG, 128, 512, 512, 0, 0, 0,
                                                        512, 512, 512, b_dg, 1.f, nullptr, 0, nullptr, nullptr, 0);
        // masked select + domain-gate rows
        e1_k<<<16384, 256, 0, stream>>>(OUTp, FO, RB, DG, dm, dsel, rm, rsel);
        // gates
        gemm_k<2, 0><<<gFlat, blk, 0, stream>>>(FO, W_mg, FG, 8192, 512, 512, 0, 0, 0,
                                                512, 512, 512, nullptr, 0.f, FB, 0, nullptr, nullptr, 0);
        gemm_k<2, 0><<<gFlat, blk, 0, stream>>>(RB, W_mg, BG, 8192, 512, 512, 0, 0, 0,
                                                512, 512, 512, nullptr, 0.f, BB, 0, nullptr, nullptr, 0);
        // Xf in place; outputs*rel
        e2_k<<<16384, 256, 0, stream>>>(FO, FG, fa, OUTp, rel, OxR);
        // DL = rel^T @ Xf
        gemm_k<0, 1><<<gBat, blk, 0, stream>>>(rel, FO, DL, 512, 512, 512, SD_, SD_, SD_,
                                               512, 512, 512, nullptr, 0.f, nullptr, 0, nullptr, nullptr, 0);
        // DL += backadj*BG*RB
        e3_k<<<16384, 256, 0, stream>>>(DL, ba, BG, RB);
        // FG <- adj @ (outputs*rel) + outputs
        gemm_k<3, 0><<<gBat, blk, 0, stream>>>(adj, OxR, FG, 512, 512, 512, SD_, SD_, SD_,
                                               512, 512, 512, nullptr, 0.f, OUTp, SD_, nullptr, nullptr, 0);
        // outs[l] = PReLU(((Ax+out)@W + 2b + DL) * invden)
        gemm_k<4, 0><<<gBat, blk, 0, stream>>>(FG, W_layers + (long)l * SD_, outsA[l], 512, 512, 512,
                                               SD_, 0, SD_, 512, 512, 512,
                                               b_layers + l * 512, 2.0f, DL, SD_, invden, prelu_a, l);
        OUTp = outsA[l];
    }

    // out = gcn + b_out, then += outs_l @ W_out[l*512:(l+1)*512]
    e4_k<<<16384, 256, 0, stream>>>(out, gcn, b_out);
    for (int l = 0; l < 3; ++l) {
        gemm_k<5, 0><<<gFlat, blk, 0, stream>>>(outsA[l], W_out + (long)l * SD_, out, 8192, 512, 512, 0, 0, 0,
                                                512, 512, 512, nullptr, 0.f, nullptr, 0, nullptr, nullptr, 0);
    }
}

// Round 2
// 892.839 us; speedup vs baseline: 2.4798x; 2.4798x over previous
//
#include <hip/hip_runtime.h>
#include <math.h>

#define SD_  (512*512)
#define BSD_ (16*512*512)

typedef short s16x8 __attribute__((ext_vector_type(8)));
typedef float f32x4 __attribute__((ext_vector_type(4)));

__device__ __forceinline__ float sigmoidf_(float x) { return 1.0f / (1.0f + __expf(-x)); }

__device__ __forceinline__ unsigned short f2bf(float f) {
    unsigned int u = __float_as_uint(f);
    u += 0x7fffu + ((u >> 16) & 1u);
    return (unsigned short)(u >> 16);
}

__device__ __forceinline__ s16x8 ldfrag(const unsigned short* S, int row, int quad) {
    union { ushort4 q[2]; s16x8 v; } u;
    u.q[0] = *(const ushort4*)&S[row * 40 + quad * 8];
    u.q[1] = *(const ushort4*)&S[row * 40 + quad * 8 + 4];
    return u.v;
}

// ---------------------------------------------------------------------------
// bf16 MFMA GEMM: C[bz] = epi( A[bz] (MxK, opt transposed) * B[bz] (KxN=512) )
// 128x128 tile, BK=32, 256 thr = 4 waves (2x2 of 64x64), fp32->bf16 on stage.
// EPI: 0=store 1=+bias 2=sigm(+Cin) 3=+Cin 4=((acc+bS*bias+Cin)*invden,PReLU)
//      6=sigm(+bias) 7=+bias+Cin
// ---------------------------------------------------------------------------
template<int EPI, int TA>
__global__ __launch_bounds__(256)
void gemm_mfma(const float* __restrict__ A, const float* __restrict__ Bm, float* __restrict__ C,
               const int M, const int K,
               const long sA, const long sB, const long sC,
               const int lda, const int ldb, const int ldc,
               const float* __restrict__ bias, const float biasScale,
               const float* __restrict__ Cin, const long sCin, const int ldcin,
               const float* __restrict__ invden,
               const float* __restrict__ prelu, const int pidx)
{
    __shared__ unsigned short As[128 * 40];
    __shared__ unsigned short Bs[128 * 40];
    const int tid = threadIdx.x;
    const int bz = blockIdx.z;
    const float* Ab = A + bz * sA;
    const float* Bb = Bm + bz * sB;
    float* Cb = C + bz * sC;
    const int m0 = blockIdx.y * 128, n0 = blockIdx.x * 128;

    const int wave = tid >> 6, lane = tid & 63;
    const int ml = lane & 15, quad = lane >> 4;
    const int wm = (wave >> 1) * 64, wn = (wave & 1) * 64;

    f32x4 acc[4][4] = {};

    // staging maps
    const int ar = tid >> 3, ak = (tid & 7) << 2;   // non-TA A: rows 0..31 (+32i), k-quad
    const int tn = tid & 127, tk2 = tid >> 7;       // transpose staging: col, k-quad parity

    float pa[16], pb[16];

    // prefetch kk = 0
    {
        const int kk = 0;
        if (TA) {
#pragma unroll
            for (int j = 0; j < 4; ++j) {
                const int kq = tk2 + 2 * j;
#pragma unroll
                for (int t = 0; t < 4; ++t)
                    pa[j * 4 + t] = Ab[(long)(kk + kq * 4 + t) * lda + m0 + tn];
            }
        } else {
#pragma unroll
            for (int i = 0; i < 4; ++i)
                *(float4*)&pa[i * 4] = *(const float4*)(Ab + (long)(m0 + ar + 32 * i) * lda + kk + ak);
        }
#pragma unroll
        for (int j = 0; j < 4; ++j) {
            const int kq = tk2 + 2 * j;
#pragma unroll
            for (int t = 0; t < 4; ++t)
                pb[j * 4 + t] = Bb[(long)(kk + kq * 4 + t) * ldb + n0 + tn];
        }
    }

    const int nkb = K >> 5;
    for (int kb = 0; kb < nkb; ++kb) {
        __syncthreads();
        if (TA) {
#pragma unroll
            for (int j = 0; j < 4; ++j) {
                const int kq = tk2 + 2 * j;
                ushort4 h = { f2bf(pa[j*4+0]), f2bf(pa[j*4+1]), f2bf(pa[j*4+2]), f2bf(pa[j*4+3]) };
                *(ushort4*)&As[tn * 40 + kq * 4] = h;
            }
        } else {
#pragma unroll
            for (int i = 0; i < 4; ++i) {
                ushort4 h = { f2bf(pa[i*4+0]), f2bf(pa[i*4+1]), f2bf(pa[i*4+2]), f2bf(pa[i*4+3]) };
                *(ushort4*)&As[(ar + 32 * i) * 40 + ak] = h;
            }
        }
#pragma unroll
        for (int j = 0; j < 4; ++j) {
            const int kq = tk2 + 2 * j;
            ushort4 h = { f2bf(pb[j*4+0]), f2bf(pb[j*4+1]), f2bf(pb[j*4+2]), f2bf(pb[j*4+3]) };
            *(ushort4*)&Bs[tn * 40 + kq * 4] = h;
        }
        __syncthreads();

        if (kb + 1 < nkb) {
            const int kk = (kb + 1) << 5;
            if (TA) {
#pragma unroll
                for (int j = 0; j < 4; ++j) {
                    const int kq = tk2 + 2 * j;
#pragma unroll
                    for (int t = 0; t < 4; ++t)
                        pa[j * 4 + t] = Ab[(long)(kk + kq * 4 + t) * lda + m0 + tn];
                }
            } else {
#pragma unroll
                for (int i = 0; i < 4; ++i)
                    *(float4*)&pa[i * 4] = *(const float4*)(Ab + (long)(m0 + ar + 32 * i) * lda + kk + ak);
            }
#pragma unroll
            for (int j = 0; j < 4; ++j) {
                const int kq = tk2 + 2 * j;
#pragma unroll
                for (int t = 0; t < 4; ++t)
                    pb[j * 4 + t] = Bb[(long)(kk + kq * 4 + t) * ldb + n0 + tn];
            }
        }

        s16x8 aF[4], bF[4];
#pragma unroll
        for (int mt = 0; mt < 4; ++mt) aF[mt] = ldfrag(As, wm + mt * 16 + ml, quad);
#pragma unroll
        for (int nt = 0; nt < 4; ++nt) bF[nt] = ldfrag(Bs, wn + nt * 16 + ml, quad);
#pragma unroll
        for (int mt = 0; mt < 4; ++mt)
#pragma unroll
            for (int nt = 0; nt < 4; ++nt)
                acc[mt][nt] = __builtin_amdgcn_mfma_f32_16x16x32_bf16(aF[mt], bF[nt], acc[mt][nt], 0, 0, 0);
    }

    const float pal = (EPI == 4) ? prelu[pidx] : 0.0f;
#pragma unroll
    for (int mt = 0; mt < 4; ++mt) {
        const int rbase = m0 + wm + mt * 16 + quad * 4;
#pragma unroll
        for (int r = 0; r < 4; ++r) {
            const int row = rbase + r;
            float idv = 1.0f;
            if (EPI == 4) idv = invden[bz * M + row];
            const long crow = (long)row * ldc;
            const long cinrow = (EPI == 2 || EPI == 3 || EPI == 4 || EPI == 7)
                                ? (bz * sCin + (long)row * ldcin) : 0;
#pragma unroll
            for (int nt = 0; nt < 4; ++nt) {
                const int col = n0 + wn + nt * 16 + ml;
                float x = acc[mt][nt][r];
                if (EPI == 1) x += bias[col];
                else if (EPI == 2) x = sigmoidf_(x + Cin[cinrow + col]);
                else if (EPI == 3) x += Cin[cinrow + col];
                else if (EPI == 4) {
                    x = (x + biasScale * bias[col] + Cin[cinrow + col]) * idv;
                    x = (x >= 0.0f) ? x : pal * x;
                }
                else if (EPI == 6) x = sigmoidf_(x + bias[col]);
                else if (EPI == 7) x += bias[col] + Cin[cinrow + col];
                Cb[crow + col] = x;
            }
        }
    }
}

// ---------------------------------------------------------------------------
// E0: per (b,s): invden, frontadj, depmap col, domain/redomain sel
// ---------------------------------------------------------------------------
__global__ __launch_bounds__(256)
void e0_k(const float* __restrict__ adj, const float* __restrict__ depmap,
          const float* __restrict__ domain_id, const float* __restrict__ redomain_id,
          float* __restrict__ invden, float* __restrict__ fa, int* __restrict__ dcol,
          int* __restrict__ dm, int* __restrict__ dsel, int* __restrict__ rm, int* __restrict__ rsel)
{
    const int bs = blockIdx.x;
    const int t = threadIdx.x;
    const float* arow = adj + (long)bs * 512;
    const float* drow = depmap + (long)bs * 512;
    __shared__ float red[256];
    __shared__ int scol;
    if (t == 0) scol = 0;
    const float a0 = arow[t], a1 = arow[t + 256];
    const float p0 = drow[t], p1 = drow[t + 256];
    if (p0 > 0.5f) scol = t;
    if (p1 > 0.5f) scol = t + 256;
    red[t] = a0 + a1;
    __syncthreads();
    for (int off = 128; off > 0; off >>= 1) { if (t < off) red[t] += red[t + off]; __syncthreads(); }
    if (t == 0) invden[bs] = 1.0f / (red[0] + 1.0f);
    __syncthreads();
    red[t] = a0 * p0 + a1 * p1;
    __syncthreads();
    for (int off = 128; off > 0; off >>= 1) { if (t < off) red[t] += red[t + off]; __syncthreads(); }
    if (t == 0) {
        fa[bs] = red[0];
        dcol[bs] = scol;
        const float* q = domain_id + (long)bs * 8;
        float s = 0.f; int sel = 0;
        for (int k = 0; k < 8; ++k) { float v = q[k]; s += v; if (v > 0.5f) sel = k; }
        dm[bs] = (s > 0.5f) ? 1 : 0; dsel[bs] = sel;
        const float* r = redomain_id + (long)bs * 8;
        s = 0.f; sel = 0;
        for (int k = 0; k < 8; ++k) { float v = r[k]; s += v; if (v > 0.5f) sel = k; }
        rm[bs] = (s > 0.5f) ? 1 : 0; rsel[bs] = sel;
    }
}

__global__ void e0b_k(const float* __restrict__ adj, const int* __restrict__ dcol, float* __restrict__ ba)
{
    const int bs = blockIdx.x * 256 + threadIdx.x;
    const int b = bs >> 9, s = bs & 511;
    ba[bs] = adj[((long)b * 512 + dcol[bs]) * 512 + s];
}

// pooling pass 1: chunked max over 32 s-rows; 256 blocks = 16 b x 16 chunks
__global__ __launch_bounds__(256)
void pool1_k(const float* __restrict__ OUT, const int ldO, const int* __restrict__ domain,
             float* __restrict__ cm)
{
    const int b = blockIdx.x >> 4, c = blockIdx.x & 15;
    const int s0 = c * 32;
    const int tid = threadIdx.x;
    __shared__ int dom[256];
    dom[tid] = domain[((long)(b * 512 + s0 + (tid >> 3))) * 8 + (tid & 7)];
    __syncthreads();
    const int d0 = tid * 2;
    float2 mx[8];
#pragma unroll
    for (int k = 0; k < 8; ++k) { mx[k].x = -1e30f; mx[k].y = -1e30f; }
    for (int s = 0; s < 32; ++s) {
        const float2 v = *(const float2*)(OUT + (long)(b * 512 + s0 + s) * ldO + d0);
        const int* ds = &dom[s * 8];
#pragma unroll
        for (int k = 0; k < 8; ++k) {
            const float vx = ds[k] ? -10000.0f : v.x;
            const float vy = ds[k] ? -10000.0f : v.y;
            mx[k].x = fmaxf(mx[k].x, vx);
            mx[k].y = fmaxf(mx[k].y, vy);
        }
    }
#pragma unroll
    for (int k = 0; k < 8; ++k)
        *(float2*)(cm + ((long)((b * 16 + c) * 8 + k)) * 512 + d0) = mx[k];
}

// pooling pass 2: reduce 16 chunks -> pooled[b*8+k][512]
__global__ void pool2_k(const float* __restrict__ cm, float* __restrict__ pooled)
{
    const int q = blockIdx.x * 256 + threadIdx.x;      // 65536
    const int b = q >> 12, k = (q >> 9) & 7, d = q & 511;
    float m = -1e30f;
    for (int c = 0; c < 16; ++c)
        m = fmaxf(m, cm[((long)((b * 16 + c) * 8 + k)) * 512 + d]);
    pooled[((long)(b * 8 + k)) * 512 + d] = m;
}

// FO = dm ? DG_row : OUTp ; RB = rm ? DG_row : RB
__global__ void e1_k(const float* __restrict__ OUTp, const int ldO,
                     float* __restrict__ FO, float* __restrict__ RB,
                     const float* __restrict__ DG, const int* __restrict__ dm, const int* __restrict__ dsel,
                     const int* __restrict__ rm, const int* __restrict__ rsel)
{
    const long idx = (long)blockIdx.x * 256 + threadIdx.x;
    const int bs = (int)(idx >> 9);
    const int d = (int)(idx & 511);
    const int b = bs >> 9;
    const float fo = dm[bs] ? DG[((long)(b * 8 + dsel[bs]) << 9) + d] : OUTp[(long)bs * ldO + d];
    const float rb = rm[bs] ? DG[((long)(b * 8 + rsel[bs]) << 9) + d] : RB[idx];
    FO[idx] = fo;
    RB[idx] = rb;
}

// FO = frontadj*FG*FO ; OxR = OUTp * rel
__global__ void e2_k(float* __restrict__ FO, const float* __restrict__ FG, const float* __restrict__ fa,
                     const float* __restrict__ OUTp, const int ldO,
                     const float* __restrict__ rel, float* __restrict__ OxR)
{
    const long idx = (long)blockIdx.x * 256 + threadIdx.x;
    const int bs = (int)(idx >> 9);
    const int d = (int)(idx & 511);
    FO[idx] = fa[bs] * FG[idx] * FO[idx];
    OxR[idx] = OUTp[(long)bs * ldO + d] * rel[idx];
}

// DL += backadj * BG * RB
__global__ void e3_k(float* __restrict__ DL, const float* __restrict__ ba,
                     const float* __restrict__ BG, const float* __restrict__ RB)
{
    const long idx = (long)blockIdx.x * 256 + threadIdx.x;
    const int bs = (int)(idx >> 9);
    DL[idx] += ba[bs] * BG[idx] * RB[idx];
}

extern "C" void kernel_launch(void* const* d_in, const int* in_sizes, int n_in,
                              void* d_out, int out_size, void* d_ws, size_t ws_size,
                              hipStream_t stream)
{
    const float* adj         = (const float*)d_in[0];
    const int*   domain      = (const int*)d_in[1];
    const float* domain_id   = (const float*)d_in[2];
    const float* redomain_id = (const float*)d_in[3];
    const float* frontrel    = (const float*)d_in[4];
    const float* backrel     = (const float*)d_in[5];
    const float* depmap      = (const float*)d_in[6];
    const float* rel         = (const float*)d_in[7];
    const float* gcn         = (const float*)d_in[8];
    const float* W_layers    = (const float*)d_in[10];
    const float* b_layers    = (const float*)d_in[11];
    const float* prelu_a     = (const float*)d_in[12];
    const float* W_dg        = (const float*)d_in[13];
    const float* b_dg        = (const float*)d_in[14];
    const float* W_mg        = (const float*)d_in[15];
    const float* b_mg        = (const float*)d_in[16];
    const float* W_out       = (const float*)d_in[17];
    const float* b_out       = (const float*)d_in[18];
    float* out = (float*)d_out;

    char* w = (char*)d_ws;
    auto alloc = [&](size_t bytes) { void* p = (void*)w; w += (bytes + 255) & ~(size_t)255; return p; };
    const size_t BSDb = (size_t)BSD_ * 4;
    float* OUTS = (float*)alloc((size_t)8192 * 1536 * 4);   // [8192][1536] concat of 3 layer outputs
    float* RB  = (float*)alloc(BSDb);
    float* FO  = (float*)alloc(BSDb);
    float* FG  = (float*)alloc(BSDb);
    float* BG  = (float*)alloc(BSDb);
    float* OxR = (float*)alloc(BSDb);
    float* DL  = (float*)alloc(BSDb);
    float* FB  = (float*)alloc(BSDb);
    float* BB  = (float*)alloc(BSDb);
    float* cm     = (float*)alloc((size_t)16 * 16 * 8 * 512 * 4);
    float* pooled = (float*)alloc((size_t)16 * 8 * 512 * 4);
    float* DG     = (float*)alloc((size_t)16 * 8 * 512 * 4);
    float* invden = (float*)alloc(8192 * 4);
    float* fa     = (float*)alloc(8192 * 4);
    float* ba     = (float*)alloc(8192 * 4);
    int* dcol = (int*)alloc(8192 * 4);
    int* dm   = (int*)alloc(8192 * 4);
    int* dsel = (int*)alloc(8192 * 4);
    int* rm   = (int*)alloc(8192 * 4);
    int* rsel = (int*)alloc(8192 * 4);

    e0_k<<<8192, 256, 0, stream>>>(adj, depmap, domain_id, redomain_id, invden, fa, dcol, dm, dsel, rm, rsel);
    e0b_k<<<32, 256, 0, stream>>>(adj, dcol, ba);

    const dim3 blk(256);
    const dim3 gFlat(4, 64, 1);
    const dim3 gBat(4, 4, 16);

    // layer-invariant: FB/BB = {front,back}rel @ W_mg[512:1024] + b_mg
    gemm_mfma<1, 0><<<gFlat, blk, 0, stream>>>(frontrel, W_mg + SD_, FB, 8192, 512, 0, 0, 0,
                                               512, 512, 512, b_mg, 1.f, nullptr, 0, 512, nullptr, nullptr, 0);
    gemm_mfma<1, 0><<<gFlat, blk, 0, stream>>>(backrel, W_mg + SD_, BB, 8192, 512, 0, 0, 0,
                                               512, 512, 512, b_mg, 1.f, nullptr, 0, 512, nullptr, nullptr, 0);

    const float* OUTp = gcn;
    int ldO = 512;
    for (int l = 0; l < 3; ++l) {
        const long sOUT = (long)512 * ldO;
        // RB = rel @ outputs
        gemm_mfma<0, 0><<<gBat, blk, 0, stream>>>(rel, OUTp, RB, 512, 512, SD_, sOUT, SD_,
                                                  512, ldO, 512, nullptr, 0.f, nullptr, 0, 512, nullptr, nullptr, 0);
        // domain max-pool + gate
        pool1_k<<<256, 256, 0, stream>>>(OUTp, ldO, domain, cm);
        pool2_k<<<256, 256, 0, stream>>>(cm, pooled);
        gemm_mfma<6, 0><<<dim3(4, 1, 1), blk, 0, stream>>>(pooled, W_dg, DG, 128, 512, 0, 0, 0,
                                                           512, 512, 512, b_dg, 1.f, nullptr, 0, 512, nullptr, nullptr, 0);
        // masked select + gate rows
        e1_k<<<16384, 256, 0, stream>>>(OUTp, ldO, FO, RB, DG, dm, dsel, rm, rsel);
        // sigmoid gates (activation half of concat; rel halves precomputed in FB/BB)
        gemm_mfma<2, 0><<<gFlat, blk, 0, stream>>>(FO, W_mg, FG, 8192, 512, 0, 0, 0,
                                                   512, 512, 512, nullptr, 0.f, FB, 0, 512, nullptr, nullptr, 0);
        gemm_mfma<2, 0><<<gFlat, blk, 0, stream>>>(RB, W_mg, BG, 8192, 512, 0, 0, 0,
                                                   512, 512, 512, nullptr, 0.f, BB, 0, 512, nullptr, nullptr, 0);
        // Xf in place; outputs*rel
        e2_k<<<16384, 256, 0, stream>>>(FO, FG, fa, OUTp, ldO, rel, OxR);
        // DL = rel^T @ Xf
        gemm_mfma<0, 1><<<gBat, blk, 0, stream>>>(rel, FO, DL, 512, 512, SD_, SD_, SD_,
                                                  512, 512, 512, nullptr, 0.f, nullptr, 0, 512, nullptr, nullptr, 0);
        // DL += backadj*BG*RB
        e3_k<<<16384, 256, 0, stream>>>(DL, ba, BG, RB);
        // FG <- adj @ (outputs*rel) + outputs
        gemm_mfma<3, 0><<<gBat, blk, 0, stream>>>(adj, OxR, FG, 512, 512, SD_, SD_, SD_,
                                                  512, 512, 512, nullptr, 0.f, OUTp, sOUT, ldO, nullptr, nullptr, 0);
        // outs[l] = PReLU(((Ax+out)@W + 2b + DL) * invden)  -> OUTS column stripe l
        gemm_mfma<4, 0><<<gBat, blk, 0, stream>>>(FG, W_layers + (long)l * SD_, OUTS + l * 512, 512, 512,
                                                  SD_, 0, (long)512 * 1536, 512, 512, 1536,
                                                  b_layers + l * 512, 2.0f, DL, SD_, 512, invden, prelu_a, l);
        OUTp = OUTS + l * 512;
        ldO = 1536;
    }

    // out = OUTS @ W_out + b_out + gcn   (single K=1536 GEMM)
    gemm_mfma<7, 0><<<gFlat, blk, 0, stream>>>(OUTS, W_out, out, 8192, 1536, 0, 0, 0,
                                               1536, 512, 512, b_out, 1.f, gcn, 0, 512, nullptr, nullptr, 0);
}

// Round 3
// 820.962 us; speedup vs baseline: 2.6969x; 1.0876x over previous
//
#include <hip/hip_runtime.h>
#include <math.h>

#define SD_  (512*512)
#define BSD_ (16*512*512)

typedef short s16x8 __attribute__((ext_vector_type(8)));
typedef float f32x4 __attribute__((ext_vector_type(4)));

__device__ __forceinline__ float sigmoidf_(float x) { return 1.0f / (1.0f + __expf(-x)); }

__device__ __forceinline__ unsigned short f2bf(float f) {
    unsigned int u = __float_as_uint(f);
    u += 0x7fffu + ((u >> 16) & 1u);
    return (unsigned short)(u >> 16);
}

// ---------------------------------------------------------------------------
// bf16 MFMA GEMM: C[bz] = epi( A[bz] (MxK, opt transposed) * B[bz] (KxN=512) )
// 128x128 tile, BK=32, 512 thr = 8 waves, each wave 64x32 (4x2 MFMA 16x16x32).
// LDS in fragment-major order: thread t writes b128 linearly at t*16B;
// frag read = one lane-linear ds_read_b128. Zero bank conflicts by design.
// EPI: 0=store 1=+bias 3=+Cin 4=((acc+bS*bias+Cin)*invden, PReLU)
//      6=sigm(+bias) 7=+bias+Cin 8=gate: sigm(acc+Cin)*sc[row]*A[row,col]
// A2: if non-null, used as A for bz==1 (two-z merged dispatches).
// ---------------------------------------------------------------------------
template<int EPI, int TA>
__global__ __launch_bounds__(512, 2)
void gemm_mfma(const float* __restrict__ A, const float* __restrict__ A2,
               const float* __restrict__ Bm, float* __restrict__ C,
               const int M, const int K,
               const long sA, const long sB, const long sC,
               const int lda, const int ldb, const int ldc,
               const float* __restrict__ bias, const float biasScale,
               const float* __restrict__ Cin, const long sCin, const int ldcin,
               const float* __restrict__ sc, const float* __restrict__ sc2,
               const float* __restrict__ invden,
               const float* __restrict__ prelu, const int pidx)
{
    __shared__ short As[4096];   // 128 rows x 32 k, fragment-major
    __shared__ short Bs[4096];
    const int tid = threadIdx.x;
    const int bz = blockIdx.z;
    const float* Ab = (A2 && bz == 1) ? A2 : (A + bz * sA);
    const float* Bb = Bm + bz * sB;
    float* Cb = C + bz * sC;
    const int m0 = blockIdx.y * 128, n0 = blockIdx.x * 128;

    const int wave = tid >> 6, lane = tid & 63;
    const int ml = lane & 15, quad = lane >> 4;
    const int wm = (wave >> 2) * 64, wn = (wave & 3) * 32;

    // staging role of thread t: row srow, k-range [sk0, sk0+8)
    const int srow = ((tid >> 6) << 4) | (tid & 15);
    const int sk0 = ((tid >> 4) & 3) << 3;

    f32x4 acc[4][2] = {};
    float pa[8], pb[8];

    // prefetch k-block 0
    {
        if (TA) {
#pragma unroll
            for (int j = 0; j < 8; ++j) pa[j] = Ab[(long)(sk0 + j) * lda + m0 + srow];
        } else {
            *(float4*)&pa[0] = *(const float4*)(Ab + (long)(m0 + srow) * lda + sk0);
            *(float4*)&pa[4] = *(const float4*)(Ab + (long)(m0 + srow) * lda + sk0 + 4);
        }
#pragma unroll
        for (int j = 0; j < 8; ++j) pb[j] = Bb[(long)(sk0 + j) * ldb + n0 + srow];
    }

    const int nkb = K >> 5;
    for (int kb = 0; kb < nkb; ++kb) {
        __syncthreads();
        {
            s16x8 ha, hb;
#pragma unroll
            for (int j = 0; j < 8; ++j) { ha[j] = (short)f2bf(pa[j]); hb[j] = (short)f2bf(pb[j]); }
            *(s16x8*)&As[tid * 8] = ha;
            *(s16x8*)&Bs[tid * 8] = hb;
        }
        __syncthreads();

        if (kb + 1 < nkb) {
            const int kk = (kb + 1) << 5;
            if (TA) {
#pragma unroll
                for (int j = 0; j < 8; ++j) pa[j] = Ab[(long)(kk + sk0 + j) * lda + m0 + srow];
            } else {
                *(float4*)&pa[0] = *(const float4*)(Ab + (long)(m0 + srow) * lda + kk + sk0);
                *(float4*)&pa[4] = *(const float4*)(Ab + (long)(m0 + srow) * lda + kk + sk0 + 4);
            }
#pragma unroll
            for (int j = 0; j < 8; ++j) pb[j] = Bb[(long)(kk + sk0 + j) * ldb + n0 + srow];
        }

        s16x8 aF[4], bF[2];
#pragma unroll
        for (int mt = 0; mt < 4; ++mt)
            aF[mt] = *(const s16x8*)&As[(((wm >> 4) + mt) * 64 + lane) * 8];
#pragma unroll
        for (int nt = 0; nt < 2; ++nt)
            bF[nt] = *(const s16x8*)&Bs[(((wn >> 4) + nt) * 64 + lane) * 8];
#pragma unroll
        for (int mt = 0; mt < 4; ++mt)
#pragma unroll
            for (int nt = 0; nt < 2; ++nt)
                acc[mt][nt] = __builtin_amdgcn_mfma_f32_16x16x32_bf16(aF[mt], bF[nt], acc[mt][nt], 0, 0, 0);
    }

    const float pal = (EPI == 4) ? prelu[pidx] : 0.0f;
    const float* scp = (EPI == 8) ? ((bz == 1) ? sc2 : sc) : nullptr;
#pragma unroll
    for (int mt = 0; mt < 4; ++mt) {
        const int rbase = m0 + wm + mt * 16 + quad * 4;
#pragma unroll
        for (int r = 0; r < 4; ++r) {
            const int row = rbase + r;
            float idv = 1.0f, scv = 0.0f;
            if (EPI == 4) idv = invden[bz * M + row];
            if (EPI == 8) scv = scp[row];
            const long crow = (long)row * ldc;
            const long cinrow = (EPI == 3 || EPI == 4 || EPI == 7 || EPI == 8)
                                ? (bz * sCin + (long)row * ldcin) : 0;
            const long arow = (EPI == 8) ? ((long)row * lda) : 0;
#pragma unroll
            for (int nt = 0; nt < 2; ++nt) {
                const int col = n0 + wn + nt * 16 + ml;
                float x = acc[mt][nt][r];
                if (EPI == 1) x += bias[col];
                else if (EPI == 3) x += Cin[cinrow + col];
                else if (EPI == 4) {
                    x = (x + biasScale * bias[col] + Cin[cinrow + col]) * idv;
                    x = (x >= 0.0f) ? x : pal * x;
                }
                else if (EPI == 6) x = sigmoidf_(x + bias[col]);
                else if (EPI == 7) x += bias[col] + Cin[cinrow + col];
                else if (EPI == 8) x = sigmoidf_(x + Cin[cinrow + col]) * scv * Ab[arow + col];
                Cb[crow + col] = x;
            }
        }
    }
}

// ---------------------------------------------------------------------------
// E0: per (b,s): invden, frontadj, depmap col, domain/redomain sel
// ---------------------------------------------------------------------------
__global__ __launch_bounds__(256)
void e0_k(const float* __restrict__ adj, const float* __restrict__ depmap,
          const float* __restrict__ domain_id, const float* __restrict__ redomain_id,
          float* __restrict__ invden, float* __restrict__ fa, int* __restrict__ dcol,
          int* __restrict__ dm, int* __restrict__ dsel, int* __restrict__ rm, int* __restrict__ rsel)
{
    const int bs = blockIdx.x;
    const int t = threadIdx.x;
    const float* arow = adj + (long)bs * 512;
    const float* drow = depmap + (long)bs * 512;
    __shared__ float red[256];
    __shared__ int scol;
    if (t == 0) scol = 0;
    const float a0 = arow[t], a1 = arow[t + 256];
    const float p0 = drow[t], p1 = drow[t + 256];
    if (p0 > 0.5f) scol = t;
    if (p1 > 0.5f) scol = t + 256;
    red[t] = a0 + a1;
    __syncthreads();
    for (int off = 128; off > 0; off >>= 1) { if (t < off) red[t] += red[t + off]; __syncthreads(); }
    if (t == 0) invden[bs] = 1.0f / (red[0] + 1.0f);
    __syncthreads();
    red[t] = a0 * p0 + a1 * p1;
    __syncthreads();
    for (int off = 128; off > 0; off >>= 1) { if (t < off) red[t] += red[t + off]; __syncthreads(); }
    if (t == 0) {
        fa[bs] = red[0];
        dcol[bs] = scol;
        const float* q = domain_id + (long)bs * 8;
        float s = 0.f; int sel = 0;
        for (int k = 0; k < 8; ++k) { float v = q[k]; s += v; if (v > 0.5f) sel = k; }
        dm[bs] = (s > 0.5f) ? 1 : 0; dsel[bs] = sel;
        const float* r = redomain_id + (long)bs * 8;
        s = 0.f; sel = 0;
        for (int k = 0; k < 8; ++k) { float v = r[k]; s += v; if (v > 0.5f) sel = k; }
        rm[bs] = (s > 0.5f) ? 1 : 0; rsel[bs] = sel;
    }
}

__global__ void e0b_k(const float* __restrict__ adj, const int* __restrict__ dcol, float* __restrict__ ba)
{
    const int bs = blockIdx.x * 256 + threadIdx.x;
    const int b = bs >> 9, s = bs & 511;
    ba[bs] = adj[((long)b * 512 + dcol[bs]) * 512 + s];
}

// pooling pass 1 + OxR = OUT*rel: 256 blocks = 16 b x 16 s-chunks of 32
__global__ __launch_bounds__(256)
void pool1_k(const float* __restrict__ OUT, const int ldO, const int* __restrict__ domain,
             const float* __restrict__ rel, float* __restrict__ cm, float* __restrict__ OxR)
{
    const int b = blockIdx.x >> 4, c = blockIdx.x & 15;
    const int s0 = c * 32;
    const int tid = threadIdx.x;
    __shared__ int dom[256];
    dom[tid] = domain[((long)(b * 512 + s0 + (tid >> 3))) * 8 + (tid & 7)];
    __syncthreads();
    const int d0 = tid * 2;
    float2 mx[8];
#pragma unroll
    for (int k = 0; k < 8; ++k) { mx[k].x = -1e30f; mx[k].y = -1e30f; }
    for (int s = 0; s < 32; ++s) {
        const int row = b * 512 + s0 + s;
        const float2 v = *(const float2*)(OUT + (long)row * ldO + d0);
        const float2 rv = *(const float2*)(rel + (long)row * 512 + d0);
        float2 o; o.x = v.x * rv.x; o.y = v.y * rv.y;
        *(float2*)(OxR + (long)row * 512 + d0) = o;
        const int* ds = &dom[s * 8];
#pragma unroll
        for (int k = 0; k < 8; ++k) {
            const float vx = ds[k] ? -10000.0f : v.x;
            const float vy = ds[k] ? -10000.0f : v.y;
            mx[k].x = fmaxf(mx[k].x, vx);
            mx[k].y = fmaxf(mx[k].y, vy);
        }
    }
#pragma unroll
    for (int k = 0; k < 8; ++k)
        *(float2*)(cm + ((long)((b * 16 + c) * 8 + k)) * 512 + d0) = mx[k];
}

__global__ void pool2_k(const float* __restrict__ cm, float* __restrict__ pooled)
{
    const int q = blockIdx.x * 256 + threadIdx.x;      // 65536
    const int b = q >> 12, k = (q >> 9) & 7, d = q & 511;
    float m = -1e30f;
    for (int c = 0; c < 16; ++c)
        m = fmaxf(m, cm[((long)((b * 16 + c) * 8 + k)) * 512 + d]);
    pooled[((long)(b * 8 + k)) * 512 + d] = m;
}

// FO = dm ? DG_row : OUTp ; RB = rm ? DG_row : RB
__global__ void e1_k(const float* __restrict__ OUTp, const int ldO,
                     float* __restrict__ FO, float* __restrict__ RB,
                     const float* __restrict__ DG, const int* __restrict__ dm, const int* __restrict__ dsel,
                     const int* __restrict__ rm, const int* __restrict__ rsel)
{
    const long idx = (long)blockIdx.x * 256 + threadIdx.x;
    const int bs = (int)(idx >> 9);
    const int d = (int)(idx & 511);
    const int b = bs >> 9;
    const float fo = dm[bs] ? DG[((long)(b * 8 + dsel[bs]) << 9) + d] : OUTp[(long)bs * ldO + d];
    const float rb = rm[bs] ? DG[((long)(b * 8 + rsel[bs]) << 9) + d] : RB[idx];
    FO[idx] = fo;
    RB[idx] = rb;
}

extern "C" void kernel_launch(void* const* d_in, const int* in_sizes, int n_in,
                              void* d_out, int out_size, void* d_ws, size_t ws_size,
                              hipStream_t stream)
{
    const float* adj         = (const float*)d_in[0];
    const int*   domain      = (const int*)d_in[1];
    const float* domain_id   = (const float*)d_in[2];
    const float* redomain_id = (const float*)d_in[3];
    const float* frontrel    = (const float*)d_in[4];
    const float* backrel     = (const float*)d_in[5];
    const float* depmap      = (const float*)d_in[6];
    const float* rel         = (const float*)d_in[7];
    const float* gcn         = (const float*)d_in[8];
    const float* W_layers    = (const float*)d_in[10];
    const float* b_layers    = (const float*)d_in[11];
    const float* prelu_a     = (const float*)d_in[12];
    const float* W_dg        = (const float*)d_in[13];
    const float* b_dg        = (const float*)d_in[14];
    const float* W_mg        = (const float*)d_in[15];
    const float* b_mg        = (const float*)d_in[16];
    const float* W_out       = (const float*)d_in[17];
    const float* b_out       = (const float*)d_in[18];
    float* out = (float*)d_out;

    char* w = (char*)d_ws;
    auto alloc = [&](size_t bytes) { void* p = (void*)w; w += (bytes + 255) & ~(size_t)255; return p; };
    const size_t BSDb = (size_t)BSD_ * 4;
    float* OUTS = (float*)alloc((size_t)8192 * 1536 * 4);   // [8192][1536] concat of layer outputs
    float* RB   = (float*)alloc(BSDb);
    float* FO   = (float*)alloc(BSDb);
    float* XB   = (float*)alloc(2 * BSDb);                  // XB then XF (z-adjacent)
    float* XF   = XB + BSD_;
    float* BB   = (float*)alloc(2 * BSDb);                  // BB then FB
    float* FB   = BB + BSD_;
    float* OxR  = (float*)alloc(BSDb);
    float* DL   = (float*)alloc(BSDb);
    float* AXO  = (float*)alloc(BSDb);
    float* cm     = (float*)alloc((size_t)16 * 16 * 8 * 512 * 4);
    float* pooled = (float*)alloc((size_t)16 * 8 * 512 * 4);
    float* DG     = (float*)alloc((size_t)16 * 8 * 512 * 4);
    float* invden = (float*)alloc(8192 * 4);
    float* fa     = (float*)alloc(8192 * 4);
    float* ba     = (float*)alloc(8192 * 4);
    int* dcol = (int*)alloc(8192 * 4);
    int* dm   = (int*)alloc(8192 * 4);
    int* dsel = (int*)alloc(8192 * 4);
    int* rm   = (int*)alloc(8192 * 4);
    int* rsel = (int*)alloc(8192 * 4);

    e0_k<<<8192, 256, 0, stream>>>(adj, depmap, domain_id, redomain_id, invden, fa, dcol, dm, dsel, rm, rsel);
    e0b_k<<<32, 256, 0, stream>>>(adj, dcol, ba);

    const dim3 blk(512);
    const dim3 gFlat(4, 64, 1);
    const dim3 gFlat2(4, 64, 2);
    const dim3 gBat(4, 4, 16);

    // BB/FB = {back,front}rel @ W_mg[512:1024] + b_mg   (z-merged)
    gemm_mfma<1, 0><<<gFlat2, blk, 0, stream>>>(backrel, frontrel, W_mg + SD_, BB, 8192, 512,
                                                0, 0, BSD_, 512, 512, 512, b_mg, 1.f,
                                                nullptr, 0, 512, nullptr, nullptr, nullptr, nullptr, 0);

    const float* OUTp = gcn;
    int ldO = 512;
    for (int l = 0; l < 3; ++l) {
        const long sOUT = (long)512 * ldO;
        // RB = rel @ outputs
        gemm_mfma<0, 0><<<gBat, blk, 0, stream>>>(rel, nullptr, OUTp, RB, 512, 512, SD_, sOUT, SD_,
                                                  512, ldO, 512, nullptr, 0.f, nullptr, 0, 512,
                                                  nullptr, nullptr, nullptr, nullptr, 0);
        // domain max-pool (+ OxR = OUT*rel) + gate
        pool1_k<<<256, 256, 0, stream>>>(OUTp, ldO, domain, rel, cm, OxR);
        pool2_k<<<256, 256, 0, stream>>>(cm, pooled);
        gemm_mfma<6, 0><<<dim3(4, 1, 1), blk, 0, stream>>>(pooled, nullptr, W_dg, DG, 128, 512, 0, 0, 0,
                                                           512, 512, 512, b_dg, 1.f, nullptr, 0, 512,
                                                           nullptr, nullptr, nullptr, nullptr, 0);
        // masked select + gate rows
        e1_k<<<16384, 256, 0, stream>>>(OUTp, ldO, FO, RB, DG, dm, dsel, rm, rsel);
        // merged gate gemm: z=0: XB = ba*sigm(RB@Wmg+BB)*RB ; z=1: XF = fa*sigm(FO@Wmg+FB)*FO
        gemm_mfma<8, 0><<<gFlat2, blk, 0, stream>>>(RB, FO, W_mg, XB, 8192, 512, 0, 0, BSD_,
                                                    512, 512, 512, nullptr, 0.f, BB, BSD_, 512,
                                                    ba, fa, nullptr, nullptr, 0);
        // DL = rel^T @ XF + XB
        gemm_mfma<3, 1><<<gBat, blk, 0, stream>>>(rel, nullptr, XF, DL, 512, 512, SD_, SD_, SD_,
                                                  512, 512, 512, nullptr, 0.f, XB, SD_, 512,
                                                  nullptr, nullptr, nullptr, nullptr, 0);
        // AXO = adj @ OxR + outputs
        gemm_mfma<3, 0><<<gBat, blk, 0, stream>>>(adj, nullptr, OxR, AXO, 512, 512, SD_, SD_, SD_,
                                                  512, 512, 512, nullptr, 0.f, OUTp, sOUT, ldO,
                                                  nullptr, nullptr, nullptr, nullptr, 0);
        // outs[l] = PReLU((AXO@W + 2b + DL) * invden) -> OUTS stripe l
        gemm_mfma<4, 0><<<gBat, blk, 0, stream>>>(AXO, nullptr, W_layers + (long)l * SD_, OUTS + l * 512,
                                                  512, 512, SD_, 0, (long)512 * 1536, 512, 512, 1536,
                                                  b_layers + l * 512, 2.0f, DL, SD_, 512,
                                                  nullptr, nullptr, invden, prelu_a, l);
        OUTp = OUTS + l * 512;
        ldO = 1536;
    }

    // out = OUTS @ W_out + b_out + gcn   (K=1536)
    gemm_mfma<7, 0><<<gFlat, blk, 0, stream>>>(OUTS, nullptr, W_out, out, 8192, 1536, 0, 0, 0,
                                               1536, 512, 512, b_out, 1.f, gcn, 0, 512,
                                               nullptr, nullptr, nullptr, nullptr, 0);
}

// Round 4
// 712.140 us; speedup vs baseline: 3.1090x; 1.1528x over previous
//
#include <hip/hip_runtime.h>
#include <math.h>

#define SD_  (512*512)
#define BSD_ (16*512*512)

typedef unsigned short u16;
typedef short s16x8 __attribute__((ext_vector_type(8)));
typedef float f32x4 __attribute__((ext_vector_type(4)));

__device__ __forceinline__ float sigmoidf_(float x) { return 1.0f / (1.0f + __expf(-x)); }

__device__ __forceinline__ u16 f2bf(float f) {
    unsigned int u = __float_as_uint(f);
    u += 0x7fffu + ((u >> 16) & 1u);
    return (u16)(u >> 16);
}
__device__ __forceinline__ float bf2f(u16 h) { return __uint_as_float((unsigned)h << 16); }

__device__ __forceinline__ void glds16(const void* g, void* l) {
    __builtin_amdgcn_global_load_lds((const __attribute__((address_space(1))) unsigned int*)g,
                                     (__attribute__((address_space(3))) unsigned int*)l, 16, 0, 0);
}

// ---------------------------------------------------------------------------
// bf16 MFMA GEMM v2. 128x128 tile, BK=32, 512thr/8 waves (wave = 64x32, 4x2 mfma).
// LDS fragment-major, double-buffered, A (and pre-transposed B) staged via
// global_load_lds dwordx4; one barrier per K-iter. Optional XCD swizzle for L2
// tile reuse. Two parameter "segments" selected by bz>=zs (merged dispatches).
// EPI: 0=store 1=+bias 3=+Cin 4=PReLU((acc+bS*bias+Cin)*invden) 6=sigm(+bias)
//      7=+bias+Cin 8=gate: sigm(acc+Cin)*sc[row]*Aeff(row,col)
// ASEL: A rows replaced by DG[seli] where selm[row] (gate-gemm; also in EPI8).
// ---------------------------------------------------------------------------
struct GP {
    const u16 *A1, *A2;  int lda1, lda2;  long sA;
    const u16 *B1, *B2;  int bt1, bt2;  int ldb1, ldb2;  long sB;
    void *C1, *C2;  int obf1, obf2;  int ldc1, ldc2;  long sC;
    const void *Ci1, *Ci2;  int cbf1, cbf2;  int ldci1, ldci2;  long sCi1, sCi2;
    const float *bias;  float bS;
    const float *sc1, *sc2;
    const int *selm1, *seli1, *selm2, *seli2;
    const float *DG;
    const float *invden, *prelu;  int pidx;
    int M, K, zs, swzY;   // swzY = log2(gridDim.y) for swizzle, -1 = off
};

template<int EPI, int ASEL>
__global__ __launch_bounds__(512, 2)
void gemm2(const GP p)
{
    __shared__ short LS[16384];   // 2 buffers x (A 4096 + B 4096) shorts
    const int tid = threadIdx.x;
    int bx, by, bz;
    if (p.swzY >= 0) {
        const int bid = blockIdx.x + 4 * (blockIdx.y + gridDim.y * blockIdx.z);
        const int ppx = (gridDim.y * gridDim.z) >> 3;
        const int xcd = bid & 7, idx = bid >> 3;
        const int pair = xcd * ppx + (idx >> 2);
        bx = idx & 3;
        by = pair & ((1 << p.swzY) - 1);
        bz = pair >> p.swzY;
    } else { bx = blockIdx.x; by = blockIdx.y; bz = blockIdx.z; }

    const int seg = (bz >= p.zs) ? 1 : 0;
    const int z = seg ? bz - p.zs : bz;
    const u16* Ab = (seg ? p.A2 : p.A1) + z * p.sA;
    const int lda = seg ? p.lda2 : p.lda1;
    const u16* Bb = (seg ? p.B2 : p.B1) + z * p.sB;
    const int bt  = seg ? p.bt2  : p.bt1;
    const int ldb = seg ? p.ldb2 : p.ldb1;

    const int m0 = by * 128, n0 = bx * 128;
    const int srow = ((tid >> 6) << 4) | (tid & 15);
    const int sk0 = ((tid >> 4) & 3) << 3;

    int aselv = 0; long dgoff = 0;
    if (ASEL) {
        const int* selm = seg ? p.selm2 : p.selm1;
        const int* seli = seg ? p.seli2 : p.seli1;
        const int row = m0 + srow;
        aselv = selm[row];
        dgoff = (long)((((row) >> 9) << 3) + seli[row]) * 512;
    }
    const u16* aRow = Ab + (long)(m0 + srow) * lda + sk0;
    const u16* bRowT = bt ? (Bb + (long)(n0 + srow) * ldb + sk0) : nullptr;

    auto stage = [&](int kk, int buf) {
        short* lsA = &LS[(buf << 13) + tid * 8];
        short* lsB = lsA + 4096;
        if (ASEL) {
            s16x8 v;
            if (aselv) {
                const float* dg = p.DG + dgoff + kk + sk0;
#pragma unroll
                for (int q = 0; q < 8; ++q) v[q] = (short)f2bf(dg[q]);
            } else v = *(const s16x8*)(aRow + kk);
            *(s16x8*)lsA = v;
        } else {
            glds16(aRow + kk, lsA);
        }
        if (bt) {
            glds16(bRowT + kk, lsB);
        } else {
            s16x8 v;
#pragma unroll
            for (int q = 0; q < 8; ++q) v[q] = (short)Bb[(long)(kk + sk0 + q) * ldb + n0 + srow];
            *(s16x8*)lsB = v;
        }
    };

    const int wave = tid >> 6, lane = tid & 63;
    const int rowSelA = (wave >> 2) << 2;   // wm/16
    const int rowSelB = (wave & 3) << 1;    // wn/16

    f32x4 acc[4][2] = {};
    stage(0, 0);
    const int nkb = p.K >> 5;
    for (int kb = 0; kb < nkb; ++kb) {
        __syncthreads();                       // drains glds (vmcnt) + ds_writes of buf[kb&1]
        if (kb + 1 < nkb) stage((kb + 1) << 5, (kb + 1) & 1);
        const short* ls = &LS[(kb & 1) << 13];
        s16x8 aF[4], bF[2];
#pragma unroll
        for (int mt = 0; mt < 4; ++mt) aF[mt] = *(const s16x8*)&ls[((rowSelA + mt) * 64 + lane) * 8];
#pragma unroll
        for (int nt = 0; nt < 2; ++nt) bF[nt] = *(const s16x8*)&ls[4096 + ((rowSelB + nt) * 64 + lane) * 8];
#pragma unroll
        for (int mt = 0; mt < 4; ++mt)
#pragma unroll
            for (int nt = 0; nt < 2; ++nt)
                acc[mt][nt] = __builtin_amdgcn_mfma_f32_16x16x32_bf16(aF[mt], bF[nt], acc[mt][nt], 0, 0, 0);
    }

    // epilogue
    const int ml = lane & 15, quad = lane >> 4;
    const int wm = (wave >> 2) * 64, wn = (wave & 3) * 32;
    u16* Cb16 = (u16*)(seg ? p.C2 : p.C1);
    float* Cb32 = (float*)(seg ? p.C2 : p.C1);
    const int obf = seg ? p.obf2 : p.obf1;
    const int ldc = seg ? p.ldc2 : p.ldc1;
    if (obf) Cb16 += z * p.sC; else Cb32 += z * p.sC;
    const u16* Ci16 = (const u16*)(seg ? p.Ci2 : p.Ci1);
    const float* Ci32 = (const float*)(seg ? p.Ci2 : p.Ci1);
    const int cbf = seg ? p.cbf2 : p.cbf1;
    const int ldci = seg ? p.ldci2 : p.ldci1;
    {
        const long sCi = seg ? p.sCi2 : p.sCi1;
        if (cbf) Ci16 += z * sCi; else Ci32 += z * sCi;
    }
    const float pal = (EPI == 4) ? p.prelu[p.pidx] : 0.0f;
    const float* scp = (EPI == 8) ? (seg ? p.sc2 : p.sc1) : nullptr;
    const int* eselm = (EPI == 8) ? (seg ? p.selm2 : p.selm1) : nullptr;
    const int* eseli = (EPI == 8) ? (seg ? p.seli2 : p.seli1) : nullptr;

#pragma unroll
    for (int mt = 0; mt < 4; ++mt) {
#pragma unroll
        for (int r = 0; r < 4; ++r) {
            const int row = m0 + wm + mt * 16 + quad * 4 + r;
            float idv = 1.0f, scv = 0.0f; int selv = 0; long dgrow = 0;
            if (EPI == 4) idv = p.invden[z * p.M + row];
            if (EPI == 8) {
                scv = scp[row]; selv = eselm[row];
                dgrow = (long)(((row >> 9) << 3) + eseli[row]) * 512;
            }
            const long crow = (long)row * ldc;
            const long cirow = (long)row * ldci;
#pragma unroll
            for (int nt = 0; nt < 2; ++nt) {
                const int col = n0 + wn + nt * 16 + ml;
                float x = acc[mt][nt][r];
                float cin = 0.0f;
                if (EPI == 3 || EPI == 4 || EPI == 7 || EPI == 8)
                    cin = cbf ? bf2f(Ci16[cirow + col]) : Ci32[cirow + col];
                if (EPI == 1) x += p.bias[col];
                else if (EPI == 3) x += cin;
                else if (EPI == 4) { x = (x + p.bS * p.bias[col] + cin) * idv; x = (x >= 0.0f) ? x : pal * x; }
                else if (EPI == 6) x = sigmoidf_(x + p.bias[col]);
                else if (EPI == 7) x += p.bias[col] + cin;
                else if (EPI == 8) {
                    const float av = selv ? p.DG[dgrow + col] : bf2f(Ab[(long)row * lda + col]);
                    x = sigmoidf_(x + cin) * scv * av;
                }
                if (obf) Cb16[crow + col] = f2bf(x); else Cb32[crow + col] = x;
            }
        }
    }
}

// --------------------------- pre-pass conversions ---------------------------
__global__ __launch_bounds__(256)
void cvt_k(const float* __restrict__ s, u16* __restrict__ d)
{
    const long i = ((long)blockIdx.x * 256 + threadIdx.x) * 4;
    const float4 v = *(const float4*)&s[i];
    ushort4 h = { f2bf(v.x), f2bf(v.y), f2bf(v.z), f2bf(v.w) };
    *(ushort4*)&d[i] = h;
}

// batched transpose+cvt: src[z] RxC fp32 -> dstT[z] CxR bf16 (+ optional normal copy)
__global__ __launch_bounds__(256)
void trcvt_k(const float* __restrict__ src, u16* __restrict__ dstT, u16* __restrict__ dstN,
             const int R, const int C, const long sS, const long sDT, const long sDN)
{
    __shared__ u16 t[64][72];
    const float* s = src + blockIdx.z * sS;
    const int r0 = blockIdx.y * 64, c0 = blockIdx.x * 64;
    const int tid = threadIdx.x;
    const int lr = tid >> 2, lc4 = (tid & 3) * 16;
#pragma unroll
    for (int j = 0; j < 4; ++j) {
        const float4 v = *(const float4*)&s[(long)(r0 + lr) * C + c0 + lc4 + j * 4];
        ushort4 h = { f2bf(v.x), f2bf(v.y), f2bf(v.z), f2bf(v.w) };
        *(ushort4*)&t[lr][lc4 + j * 4] = h;
        if (dstN) *(ushort4*)&dstN[blockIdx.z * sDN + (long)(r0 + lr) * C + c0 + lc4 + j * 4] = h;
    }
    __syncthreads();
    const int lcol = tid >> 2, rc = (tid & 3) * 16;
#pragma unroll
    for (int j = 0; j < 2; ++j) {
        s16x8 v;
#pragma unroll
        for (int q = 0; q < 8; ++q) v[q] = (short)t[rc + j * 8 + q][lcol];
        *(s16x8*)&dstT[blockIdx.z * sDT + (long)(c0 + lcol) * R + r0 + rc + j * 8] = v;
    }
}

// ---------------------------------------------------------------------------
// E0: per (b,s): invden, frontadj, depmap col, domain/redomain sel
// ---------------------------------------------------------------------------
__global__ __launch_bounds__(256)
void e0_k(const float* __restrict__ adj, const float* __restrict__ depmap,
          const float* __restrict__ domain_id, const float* __restrict__ redomain_id,
          float* __restrict__ invden, float* __restrict__ fa, int* __restrict__ dcol,
          int* __restrict__ dm, int* __restrict__ dsel, int* __restrict__ rm, int* __restrict__ rsel)
{
    const int bs = blockIdx.x;
    const int t = threadIdx.x;
    const float* arow = adj + (long)bs * 512;
    const float* drow = depmap + (long)bs * 512;
    __shared__ float red[256];
    __shared__ int scol;
    if (t == 0) scol = 0;
    const float a0 = arow[t], a1 = arow[t + 256];
    const float p0 = drow[t], p1 = drow[t + 256];
    if (p0 > 0.5f) scol = t;
    if (p1 > 0.5f) scol = t + 256;
    red[t] = a0 + a1;
    __syncthreads();
    for (int off = 128; off > 0; off >>= 1) { if (t < off) red[t] += red[t + off]; __syncthreads(); }
    if (t == 0) invden[bs] = 1.0f / (red[0] + 1.0f);
    __syncthreads();
    red[t] = a0 * p0 + a1 * p1;
    __syncthreads();
    for (int off = 128; off > 0; off >>= 1) { if (t < off) red[t] += red[t + off]; __syncthreads(); }
    if (t == 0) {
        fa[bs] = red[0];
        dcol[bs] = scol;
        const float* q = domain_id + (long)bs * 8;
        float s = 0.f; int sel = 0;
        for (int k = 0; k < 8; ++k) { float v = q[k]; s += v; if (v > 0.5f) sel = k; }
        dm[bs] = (s > 0.5f) ? 1 : 0; dsel[bs] = sel;
        const float* r = redomain_id + (long)bs * 8;
        s = 0.f; sel = 0;
        for (int k = 0; k < 8; ++k) { float v = r[k]; s += v; if (v > 0.5f) sel = k; }
        rm[bs] = (s > 0.5f) ? 1 : 0; rsel[bs] = sel;
    }
}

__global__ void e0b_k(const float* __restrict__ adj, const int* __restrict__ dcol, float* __restrict__ ba)
{
    const int bs = blockIdx.x * 256 + threadIdx.x;
    const int b = bs >> 9, s = bs & 511;
    ba[bs] = adj[((long)b * 512 + dcol[bs]) * 512 + s];
}

// pool pass1 (chunked masked max) + OxR^T = (OUT .* rel)^T, all bf16
__global__ __launch_bounds__(256)
void pool1_k(const u16* __restrict__ OUT, const int ldO, const int* __restrict__ domain,
             const u16* __restrict__ relb, u16* __restrict__ cm, u16* __restrict__ OxRT)
{
    const int b = blockIdx.x >> 4, c = blockIdx.x & 15;
    const int s0 = c * 32, tid = threadIdx.x;
    __shared__ int dom[256];
    dom[tid] = domain[((long)(b * 512 + s0 + (tid >> 3))) * 8 + (tid & 7)];
    __syncthreads();
    const int d0 = tid * 2;
    float mxa[8], mxb[8];
#pragma unroll
    for (int k = 0; k < 8; ++k) { mxa[k] = -10000.0f; mxb[k] = -10000.0f; }
    s16x8 pA[4], pB[4];
#pragma unroll
    for (int s = 0; s < 32; ++s) {
        const int row = b * 512 + s0 + s;
        const unsigned uv = *(const unsigned*)&OUT[(long)row * ldO + d0];
        const unsigned rv = *(const unsigned*)&relb[(long)row * 512 + d0];
        const float vx = bf2f((u16)(uv & 0xffff)), vy = bf2f((u16)(uv >> 16));
        const float rx = bf2f((u16)(rv & 0xffff)), ry = bf2f((u16)(rv >> 16));
        pA[s >> 3][s & 7] = (short)f2bf(vx * rx);
        pB[s >> 3][s & 7] = (short)f2bf(vy * ry);
        const int* ds = &dom[s * 8];
#pragma unroll
        for (int k = 0; k < 8; ++k) {
            mxa[k] = fmaxf(mxa[k], ds[k] ? -10000.0f : vx);
            mxb[k] = fmaxf(mxb[k], ds[k] ? -10000.0f : vy);
        }
    }
#pragma unroll
    for (int j = 0; j < 4; ++j) *(s16x8*)&OxRT[((long)b * 512 + d0) * 512 + s0 + j * 8] = pA[j];
#pragma unroll
    for (int j = 0; j < 4; ++j) *(s16x8*)&OxRT[((long)b * 512 + d0 + 1) * 512 + s0 + j * 8] = pB[j];
#pragma unroll
    for (int k = 0; k < 8; ++k) {
        ushort2 h = { f2bf(mxa[k]), f2bf(mxb[k]) };
        *(ushort2*)&cm[((long)((b * 16 + c) * 8 + k)) * 512 + d0] = h;
    }
}

__global__ void pool2_k(const u16* __restrict__ cm, u16* __restrict__ pooled)
{
    const int q = blockIdx.x * 256 + threadIdx.x;      // 65536
    const int b = q >> 12, k = (q >> 9) & 7, d = q & 511;
    float m = -1e30f;
    for (int c = 0; c < 16; ++c)
        m = fmaxf(m, bf2f(cm[((long)((b * 16 + c) * 8 + k)) * 512 + d]));
    pooled[((long)(b * 8 + k)) * 512 + d] = f2bf(m);
}

extern "C" void kernel_launch(void* const* d_in, const int* in_sizes, int n_in,
                              void* d_out, int out_size, void* d_ws, size_t ws_size,
                              hipStream_t stream)
{
    const float* adj         = (const float*)d_in[0];
    const int*   domain      = (const int*)d_in[1];
    const float* domain_id   = (const float*)d_in[2];
    const float* redomain_id = (const float*)d_in[3];
    const float* frontrel    = (const float*)d_in[4];
    const float* backrel     = (const float*)d_in[5];
    const float* depmap      = (const float*)d_in[6];
    const float* rel         = (const float*)d_in[7];
    const float* gcn         = (const float*)d_in[8];
    const float* W_layers    = (const float*)d_in[10];
    const float* b_layers    = (const float*)d_in[11];
    const float* prelu_a     = (const float*)d_in[12];
    const float* W_dg        = (const float*)d_in[13];
    const float* b_dg        = (const float*)d_in[14];
    const float* W_mg        = (const float*)d_in[15];
    const float* b_mg        = (const float*)d_in[16];
    const float* W_out       = (const float*)d_in[17];
    const float* b_out       = (const float*)d_in[18];
    float* out = (float*)d_out;

    char* w = (char*)d_ws;
    auto alloc = [&](size_t bytes) { void* p = (void*)w; w += (bytes + 255) & ~(size_t)255; return p; };
    const size_t Bb = (size_t)BSD_ * 2;                  // bf16 [16][512][512]
    u16* OUTS_bf = (u16*)alloc((size_t)8192 * 1536 * 2);
    u16* RB_bf   = (u16*)alloc(Bb);
    u16* XB_bf   = (u16*)alloc(Bb);
    u16* XF_bf   = (u16*)alloc(Bb);
    u16* OxRT_bf = (u16*)alloc(Bb);
    u16* DL_bf   = (u16*)alloc(Bb);
    u16* AXO_bf  = (u16*)alloc(Bb);
    u16* BB_bf   = (u16*)alloc(Bb);
    u16* FB_bf   = (u16*)alloc(Bb);
    u16* rel_bf  = (u16*)alloc(Bb);
    u16* relT_bf = (u16*)alloc(Bb);
    u16* adj_bf  = (u16*)alloc(Bb);
    u16* gcn_bf  = (u16*)alloc(Bb);
    u16* frel_bf = (u16*)alloc(Bb);
    u16* brel_bf = (u16*)alloc(Bb);
    u16* WmgT1 = (u16*)alloc((size_t)SD_ * 2);
    u16* WmgT2 = (u16*)alloc((size_t)SD_ * 2);
    u16* WdgT  = (u16*)alloc((size_t)SD_ * 2);
    u16* WlT   = (u16*)alloc((size_t)3 * SD_ * 2);
    u16* WoutT = (u16*)alloc((size_t)512 * 1536 * 2);
    u16* cm     = (u16*)alloc((size_t)16 * 16 * 8 * 512 * 2);
    u16* pooled = (u16*)alloc((size_t)16 * 8 * 512 * 2);
    float* DG     = (float*)alloc((size_t)16 * 8 * 512 * 4);
    float* invden = (float*)alloc(8192 * 4);
    float* fa     = (float*)alloc(8192 * 4);
    float* ba     = (float*)alloc(8192 * 4);
    int* dcol = (int*)alloc(8192 * 4);
    int* dm   = (int*)alloc(8192 * 4);
    int* dsel = (int*)alloc(8192 * 4);
    int* rm   = (int*)alloc(8192 * 4);
    int* rsel = (int*)alloc(8192 * 4);

    // ---- pre-pass ----
    cvt_k<<<4096, 256, 0, stream>>>(adj, adj_bf);
    cvt_k<<<4096, 256, 0, stream>>>(gcn, gcn_bf);
    cvt_k<<<4096, 256, 0, stream>>>(frontrel, frel_bf);
    cvt_k<<<4096, 256, 0, stream>>>(backrel, brel_bf);
    trcvt_k<<<dim3(8, 8, 16), 256, 0, stream>>>(rel, relT_bf, rel_bf, 512, 512, SD_, SD_, SD_);
    trcvt_k<<<dim3(8, 8, 1), 256, 0, stream>>>(W_mg, WmgT1, nullptr, 512, 512, 0, 0, 0);
    trcvt_k<<<dim3(8, 8, 1), 256, 0, stream>>>(W_mg + SD_, WmgT2, nullptr, 512, 512, 0, 0, 0);
    trcvt_k<<<dim3(8, 8, 1), 256, 0, stream>>>(W_dg, WdgT, nullptr, 512, 512, 0, 0, 0);
    trcvt_k<<<dim3(8, 8, 3), 256, 0, stream>>>(W_layers, WlT, nullptr, 512, 512, SD_, SD_, 0);
    trcvt_k<<<dim3(8, 24, 1), 256, 0, stream>>>(W_out, WoutT, nullptr, 1536, 512, 0, 0, 0);
    e0_k<<<8192, 256, 0, stream>>>(adj, depmap, domain_id, redomain_id, invden, fa, dcol, dm, dsel, rm, rsel);
    e0b_k<<<32, 256, 0, stream>>>(adj, dcol, ba);

    const dim3 blk(512);

    // BB/FB = {back,front}rel @ W_mg[512:1024] + b_mg   (z=2 merged)
    {
        GP p{};
        p.A1 = brel_bf; p.A2 = frel_bf; p.lda1 = p.lda2 = 512; p.sA = 0;
        p.B1 = p.B2 = WmgT2; p.bt1 = p.bt2 = 1; p.ldb1 = p.ldb2 = 512; p.sB = 0;
        p.C1 = BB_bf; p.C2 = FB_bf; p.obf1 = p.obf2 = 1; p.ldc1 = p.ldc2 = 512; p.sC = 0;
        p.bias = b_mg; p.M = 8192; p.K = 512; p.zs = 1; p.swzY = 6;
        gemm2<1, 0><<<dim3(4, 64, 2), blk, 0, stream>>>(p);
    }

    for (int l = 0; l < 3; ++l) {
        const u16* OUTp = (l == 0) ? gcn_bf : (OUTS_bf + (l - 1) * 512);
        const int ldO = (l == 0) ? 512 : 1536;
        const long sO = (long)512 * ldO;

        // RB = rel @ outputs  (bf16)
        {
            GP p{};
            p.A1 = rel_bf; p.lda1 = 512; p.sA = SD_;
            p.B1 = OUTp; p.bt1 = 0; p.ldb1 = ldO; p.sB = sO;
            p.C1 = RB_bf; p.obf1 = 1; p.ldc1 = 512; p.sC = SD_;
            p.M = 512; p.K = 512; p.zs = 16; p.swzY = 2;
            gemm2<0, 0><<<dim3(4, 4, 16), blk, 0, stream>>>(p);
        }
        // pool + OxR^T ; reduce ; DG = sigm(pooled @ W_dg + b_dg)
        pool1_k<<<256, 256, 0, stream>>>(OUTp, ldO, domain, rel_bf, cm, OxRT_bf);
        pool2_k<<<256, 256, 0, stream>>>(cm, pooled);
        {
            GP p{};
            p.A1 = pooled; p.lda1 = 512; p.B1 = WdgT; p.bt1 = 1; p.ldb1 = 512;
            p.C1 = DG; p.obf1 = 0; p.ldc1 = 512;
            p.bias = b_dg; p.M = 128; p.K = 512; p.zs = 1; p.swzY = -1;
            gemm2<6, 0><<<dim3(4, 1, 1), blk, 0, stream>>>(p);
        }
        // merged gates: z0: XB = ba*sigm(RBeff@W1+BB)*RBeff ; z1: XF = fa*sigm(FOeff@W1+FB)*FOeff
        {
            GP p{};
            p.A1 = RB_bf; p.lda1 = 512; p.A2 = OUTp; p.lda2 = ldO; p.sA = 0;
            p.selm1 = rm; p.seli1 = rsel; p.selm2 = dm; p.seli2 = dsel; p.DG = DG;
            p.B1 = p.B2 = WmgT1; p.bt1 = p.bt2 = 1; p.ldb1 = p.ldb2 = 512; p.sB = 0;
            p.Ci1 = BB_bf; p.Ci2 = FB_bf; p.cbf1 = p.cbf2 = 1; p.ldci1 = p.ldci2 = 512; p.sCi1 = p.sCi2 = 0;
            p.C1 = XB_bf; p.C2 = XF_bf; p.obf1 = p.obf2 = 1; p.ldc1 = p.ldc2 = 512; p.sC = 0;
            p.sc1 = ba; p.sc2 = fa; p.M = 8192; p.K = 512; p.zs = 1; p.swzY = 6;
            gemm2<8, 1><<<dim3(4, 64, 2), blk, 0, stream>>>(p);
        }
        // merged: z<16: DL = rel^T @ XF + XB ; z>=16: AXO = adj @ OxR + outputs
        {
            GP p{};
            p.A1 = relT_bf; p.lda1 = 512; p.A2 = adj_bf; p.lda2 = 512; p.sA = SD_;
            p.B1 = XF_bf; p.bt1 = 0; p.ldb1 = 512;
            p.B2 = OxRT_bf; p.bt2 = 1; p.ldb2 = 512; p.sB = SD_;
            p.Ci1 = XB_bf; p.cbf1 = 1; p.ldci1 = 512; p.sCi1 = SD_;
            p.Ci2 = OUTp; p.cbf2 = 1; p.ldci2 = ldO; p.sCi2 = sO;
            p.C1 = DL_bf; p.C2 = AXO_bf; p.obf1 = p.obf2 = 1; p.ldc1 = p.ldc2 = 512; p.sC = SD_;
            p.M = 512; p.K = 512; p.zs = 16; p.swzY = 2;
            gemm2<3, 0><<<dim3(4, 4, 32), blk, 0, stream>>>(p);
        }
        // outs[l] = PReLU((AXO@W + 2b + DL)*invden) -> OUTS stripe l (bf16)
        {
            GP p{};
            p.A1 = AXO_bf; p.lda1 = 512; p.sA = SD_;
            p.B1 = WlT + (long)l * SD_; p.bt1 = 1; p.ldb1 = 512; p.sB = 0;
            p.Ci1 = DL_bf; p.cbf1 = 1; p.ldci1 = 512; p.sCi1 = SD_;
            p.C1 = OUTS_bf + l * 512; p.obf1 = 1; p.ldc1 = 1536; p.sC = (long)512 * 1536;
            p.bias = b_layers + l * 512; p.bS = 2.0f;
            p.invden = invden; p.prelu = prelu_a; p.pidx = l;
            p.M = 512; p.K = 512; p.zs = 16; p.swzY = 2;
            gemm2<4, 0><<<dim3(4, 4, 16), blk, 0, stream>>>(p);
        }
    }

    // out = OUTS @ W_out + b_out + gcn   (K=1536, fp32 out)
    {
        GP p{};
        p.A1 = OUTS_bf; p.lda1 = 1536; p.sA = 0;
        p.B1 = WoutT; p.bt1 = 1; p.ldb1 = 1536; p.sB = 0;
        p.Ci1 = gcn; p.cbf1 = 0; p.ldci1 = 512; p.sCi1 = 0;
        p.C1 = out; p.obf1 = 0; p.ldc1 = 512; p.sC = 0;
        p.bias = b_out; p.M = 8192; p.K = 1536; p.zs = 1; p.swzY = 6;
        gemm2<7, 0><<<dim3(4, 64, 1), blk, 0, stream>>>(p);
    }
}